// Round 1
// 836.017 us; speedup vs baseline: 1.1329x; 1.1329x over previous
//
#include <hip/hip_runtime.h>
#include <hip/hip_bf16.h>
#include <cstdint>
#include <cstddef>

#define NMAT 4096

typedef __bf16 bf16x8 __attribute__((ext_vector_type(8)));
typedef float f32x4 __attribute__((ext_vector_type(4)));

__device__ inline float fastrcp(float x) { return __builtin_amdgcn_rcpf(x); }

// ---------- prep: row max + exp + bf16 store; also init v1 = 1.0 ----------
__global__ __launch_bounds__(256) void prep_kernel(const float* __restrict__ M,
                                                   __bf16* __restrict__ m0,
                                                   float* __restrict__ v1) {
    const int row = blockIdx.x, t = threadIdx.x;
    if (blockIdx.x < 16) v1[blockIdx.x * 256 + t] = 1.0f;
    const float4* rp = (const float4*)(M + (size_t)row * NMAT);
    float4 p[4];
#pragma unroll
    for (int s = 0; s < 4; s++) p[s] = rp[t * 4 + s];
    float mx = -1e30f;
#pragma unroll
    for (int s = 0; s < 4; s++)
        mx = fmaxf(mx, fmaxf(fmaxf(p[s].x, p[s].y), fmaxf(p[s].z, p[s].w)));
#pragma unroll
    for (int off = 32; off; off >>= 1) mx = fmaxf(mx, __shfl_down(mx, off));
    __shared__ float wm[4];
    if ((t & 63) == 0) wm[t >> 6] = mx;
    __syncthreads();
    mx = fmaxf(fmaxf(wm[0], wm[1]), fmaxf(wm[2], wm[3]));
    bf16x8 o[2];
#pragma unroll
    for (int s = 0; s < 4; s++) {
        o[s >> 1][(s & 1) * 4 + 0] = (__bf16)__expf(0.5f * (p[s].x - mx));
        o[s >> 1][(s & 1) * 4 + 1] = (__bf16)__expf(0.5f * (p[s].y - mx));
        o[s >> 1][(s & 1) * 4 + 2] = (__bf16)__expf(0.5f * (p[s].z - mx));
        o[s >> 1][(s & 1) * 4 + 3] = (__bf16)__expf(0.5f * (p[s].w - mx));
    }
    bf16x8* op = (bf16x8*)(m0 + (size_t)row * NMAT + t * 16);
    op[0] = o[0];
    op[1] = o[1];
}

// ---------- L = sigmoid(5*lower) * tril, bf16 ----------
__global__ __launch_bounds__(256) void lmask_kernel(const float* __restrict__ Lo,
                                                    __bf16* __restrict__ Lm) {
    const int row = blockIdx.x, t = threadIdx.x;
    const float4* rp = (const float4*)(Lo + (size_t)row * NMAT);
    bf16x8 o[2];
#pragma unroll
    for (int s = 0; s < 4; s++) {
        float4 p = rp[t * 4 + s];
        int c0 = t * 16 + s * 4;
        float f0 = (c0 + 0 <= row) ? fastrcp(1.f + __expf(-5.f * p.x)) : 0.f;
        float f1 = (c0 + 1 <= row) ? fastrcp(1.f + __expf(-5.f * p.y)) : 0.f;
        float f2 = (c0 + 2 <= row) ? fastrcp(1.f + __expf(-5.f * p.z)) : 0.f;
        float f3 = (c0 + 3 <= row) ? fastrcp(1.f + __expf(-5.f * p.w)) : 0.f;
        o[s >> 1][(s & 1) * 4 + 0] = (__bf16)f0;
        o[s >> 1][(s & 1) * 4 + 1] = (__bf16)f1;
        o[s >> 1][(s & 1) * 4 + 2] = (__bf16)f2;
        o[s >> 1][(s & 1) * 4 + 3] = (__bf16)f3;
    }
    bf16x8* op = (bf16x8*)(Lm + (size_t)row * NMAT + t * 16);
    op[0] = o[0];
    op[1] = o[1];
}

// ---------- u_i = sum_j m0[i,j] / vprev[j]; also zero vzero ----------
__global__ __launch_bounds__(256) void rowdots_kernel(const __bf16* __restrict__ m0,
                                                      const float* __restrict__ vprev,
                                                      float* __restrict__ u,
                                                      float* __restrict__ vzero) {
    __shared__ float cs[NMAT];
    const int t = threadIdx.x;
    if (blockIdx.x < 16) vzero[blockIdx.x * 256 + t] = 0.f;
#pragma unroll
    for (int s = 0; s < 16; s++) {
        int j = s * 256 + t;
        cs[j] = fastrcp(vprev[j]);
    }
    __syncthreads();
    const int wave = t >> 6, lane = t & 63;
    const int row = blockIdx.x * 4 + wave;
    const __bf16* rp = m0 + (size_t)row * NMAT;
    float sum = 0.f;
#pragma unroll
    for (int jj = 0; jj < NMAT; jj += 512) {
        int j = jj + lane * 8;
        bf16x8 mv = *(const bf16x8*)(rp + j);
        float4 c0 = *(const float4*)(cs + j);
        float4 c1 = *(const float4*)(cs + j + 4);
        sum += (float)mv[0] * c0.x + (float)mv[1] * c0.y + (float)mv[2] * c0.z +
               (float)mv[3] * c0.w + (float)mv[4] * c1.x + (float)mv[5] * c1.y +
               (float)mv[6] * c1.z + (float)mv[7] * c1.w;
    }
#pragma unroll
    for (int off = 32; off; off >>= 1) sum += __shfl_down(sum, off);
    if (lane == 0) u[row] = sum;
}

// ---------- vnew_j += sum_i m0[i,j] / u[i]  (vnew pre-zeroed) ----------
__global__ __launch_bounds__(256) void colsums_kernel(const __bf16* __restrict__ m0,
                                                      const float* __restrict__ u,
                                                      float* __restrict__ vnew) {
    const int t = threadIdx.x;
    const int j0 = blockIdx.x * 1024 + t * 4;
    const int i0 = blockIdx.y * 64;
    float a0 = 0, a1 = 0, a2 = 0, a3 = 0;
    for (int i = i0; i < i0 + 64; i++) {
        float r = fastrcp(u[i]);
        ushort4 mv = *(const ushort4*)(m0 + (size_t)i * NMAT + j0);
        a0 += r * __uint_as_float((unsigned)mv.x << 16);
        a1 += r * __uint_as_float((unsigned)mv.y << 16);
        a2 += r * __uint_as_float((unsigned)mv.z << 16);
        a3 += r * __uint_as_float((unsigned)mv.w << 16);
    }
    atomicAdd(vnew + j0 + 0, a0);
    atomicAdd(vnew + j0 + 1, a1);
    atomicAdd(vnew + j0 + 2, a2);
    atomicAdd(vnew + j0 + 3, a3);
}

// ---------- r = 1/u (in place); c = 1/v ----------
__global__ __launch_bounds__(256) void invvec_kernel(float* __restrict__ u,
                                                     const float* __restrict__ v,
                                                     float* __restrict__ c) {
    const int i = blockIdx.x * 256 + threadIdx.x;
    u[i] = fastrcp(u[i]);
    c[i] = fastrcp(v[i]);
}

// ---------- m[i,j] = m0[i,j] * r_i * c_j (in place, bf16) ----------
__global__ __launch_bounds__(256) void rescale_kernel(__bf16* __restrict__ m,
                                                      const float* __restrict__ r,
                                                      const float* __restrict__ c) {
    const int row = blockIdx.x, t = threadIdx.x;
    const float rr = r[row];
    bf16x8* mp = (bf16x8*)(m + (size_t)row * NMAT + t * 16);
    bf16x8 a = mp[0], b = mp[1];
    const float4* cp = (const float4*)(c + t * 16);
    float4 c0 = cp[0], c1 = cp[1], c2 = cp[2], c3 = cp[3];
    bf16x8 oa, ob;
    oa[0] = (__bf16)(rr * c0.x * (float)a[0]);
    oa[1] = (__bf16)(rr * c0.y * (float)a[1]);
    oa[2] = (__bf16)(rr * c0.z * (float)a[2]);
    oa[3] = (__bf16)(rr * c0.w * (float)a[3]);
    oa[4] = (__bf16)(rr * c1.x * (float)a[4]);
    oa[5] = (__bf16)(rr * c1.y * (float)a[5]);
    oa[6] = (__bf16)(rr * c1.z * (float)a[6]);
    oa[7] = (__bf16)(rr * c1.w * (float)a[7]);
    ob[0] = (__bf16)(rr * c2.x * (float)b[0]);
    ob[1] = (__bf16)(rr * c2.y * (float)b[1]);
    ob[2] = (__bf16)(rr * c2.z * (float)b[2]);
    ob[3] = (__bf16)(rr * c2.w * (float)b[3]);
    ob[4] = (__bf16)(rr * c3.x * (float)b[4]);
    ob[5] = (__bf16)(rr * c3.y * (float)b[5]);
    ob[6] = (__bf16)(rr * c3.z * (float)b[6]);
    ob[7] = (__bf16)(rr * c3.w * (float)b[7]);
    mp[0] = oa;
    mp[1] = ob;
}

// ---------- NT GEMM: C[i,j] = sum_k A[i,k]*B[j,k] ----------
// 256x256 tile, BK=32, 4 LDS buffers (lookahead-3 prefetch), 512 threads (8 waves 2x4),
// counted vmcnt (never 0 in steady state), raw s_barrier + lgkmcnt, setprio MFMA clusters.
// K-accumulation order identical to the previous 128^2 kernel (bitwise-same numerics).
template <int OUTBF>
__global__ __launch_bounds__(512, 2) void gemm_nt(const __bf16* __restrict__ A,
                                                  const __bf16* __restrict__ B,
                                                  void* __restrict__ C) {
    // 4 buffers x (A 256x32 + B 256x32) bf16 = 4 x 32 KiB = 128 KiB
    __shared__ __bf16 lds[4 * 16384];
    const int t = threadIdx.x;
    const int lane = t & 63, wave = t >> 6;
    const int wm = wave >> 2, wn = wave & 3;   // 2 x 4 wave grid
    const int fr = lane & 15, fq = lane >> 4;  // MFMA fragment coords

    // XCD-aware bijective block swizzle: 256 blocks, 8 XCDs, 32 contiguous tiles/XCD
    const int bid = blockIdx.y * 16 + blockIdx.x;
    const int wg = (bid & 7) * 32 + (bid >> 3);
    const int bi = (wg >> 4) * 256;
    const int bj = (wg & 15) * 256;

    // staging geometry: per half (A or B) each wave issues 2 global_load_lds,
    // each covering 16 rows x 64B (1 KiB linear LDS chunk, lane l -> base + l*16)
    const int srow = lane >> 2;       // 0..15 row within 16-row chunk
    const int scol = (lane & 3) * 8;  // element col within 32-wide K-tile
    const int sub = wave * 2;

    f32x4 acc[8][4];
#pragma unroll
    for (int m = 0; m < 8; m++)
#pragma unroll
        for (int n = 0; n < 4; n++) acc[m][n] = (f32x4){0.f, 0.f, 0.f, 0.f};

    auto stageA = [&](int kt, int buf) {
#pragma unroll
        for (int q = 0; q < 2; q++) {
            const int row = (sub + q) * 16 + srow;
            const __bf16* g = A + (size_t)(bi + row) * NMAT + kt * 32 + scol;
            char* l = (char*)lds + buf * 32768 + (sub + q) * 1024;
            __builtin_amdgcn_global_load_lds(
                (__attribute__((address_space(1))) void*)g,
                (__attribute__((address_space(3))) void*)l, 16, 0, 0);
        }
    };
    auto stageB = [&](int kt, int buf) {
#pragma unroll
        for (int q = 0; q < 2; q++) {
            const int row = (sub + q) * 16 + srow;
            const __bf16* g = B + (size_t)(bj + row) * NMAT + kt * 32 + scol;
            char* l = (char*)lds + buf * 32768 + 16384 + (sub + q) * 1024;
            __builtin_amdgcn_global_load_lds(
                (__attribute__((address_space(1))) void*)g,
                (__attribute__((address_space(3))) void*)l, 16, 0, 0);
        }
    };

    // prologue: stage K-tiles 0,1,2 into bufs 0,1,2 (4 loads/wave each)
    stageA(0, 0); stageB(0, 0);
    stageA(1, 1); stageB(1, 1);
    stageA(2, 2); stageB(2, 2);
    asm volatile("s_waitcnt vmcnt(8)" ::: "memory");  // kt0 landed; kt1,kt2 in flight
    __builtin_amdgcn_s_barrier();

    const int NK = NMAT / 32;  // 128
    for (int kt = 0; kt < NK; ++kt) {
        const __bf16* bufA = lds + (kt & 3) * 16384;
        const __bf16* bufB = bufA + 8192;
        const int sb = (kt + 3) & 3;          // stage target: buffer vacated last iter
        const bool dstage = (kt + 3) < NK;    // uniform

        // ---- phase 0: ds_read B (4) + A lower half (4); issue A prefetch ----
        bf16x8 bfr[4], af0[4];
#pragma unroll
        for (int n = 0; n < 4; n++)
            bfr[n] = *(const bf16x8*)(bufB + (wn * 64 + n * 16 + fr) * 32 + fq * 8);
#pragma unroll
        for (int m = 0; m < 4; m++)
            af0[m] = *(const bf16x8*)(bufA + (wm * 128 + m * 16 + fr) * 32 + fq * 8);
        if (dstage) stageA(kt + 3, sb);
        __builtin_amdgcn_s_barrier();
        asm volatile("s_waitcnt lgkmcnt(0)" ::: "memory");
        __builtin_amdgcn_sched_barrier(0);
        __builtin_amdgcn_s_setprio(1);
#pragma unroll
        for (int m = 0; m < 4; m++)
#pragma unroll
            for (int n = 0; n < 4; n++)
                acc[m][n] = __builtin_amdgcn_mfma_f32_16x16x32_bf16(af0[m], bfr[n],
                                                                    acc[m][n], 0, 0, 0);
        __builtin_amdgcn_s_setprio(0);
        __builtin_amdgcn_sched_barrier(0);

        // ---- phase 1: ds_read A upper half (4); issue B prefetch ----
        bf16x8 af1[4];
#pragma unroll
        for (int m = 0; m < 4; m++)
            af1[m] = *(const bf16x8*)(bufA + (wm * 128 + (m + 4) * 16 + fr) * 32 + fq * 8);
        if (dstage) stageB(kt + 3, sb);
        __builtin_amdgcn_s_barrier();
        asm volatile("s_waitcnt lgkmcnt(0)" ::: "memory");
        __builtin_amdgcn_sched_barrier(0);
        __builtin_amdgcn_s_setprio(1);
#pragma unroll
        for (int m = 0; m < 4; m++)
#pragma unroll
            for (int n = 0; n < 4; n++)
                acc[m + 4][n] = __builtin_amdgcn_mfma_f32_16x16x32_bf16(af1[m], bfr[n],
                                                                        acc[m + 4][n], 0, 0, 0);
        __builtin_amdgcn_s_setprio(0);
        __builtin_amdgcn_sched_barrier(0);

        // ---- checkpoint: ensure kt+1 landed; keep kt+2/kt+3 in flight ----
        if (kt + 3 < NK) {
            asm volatile("s_waitcnt vmcnt(8)" ::: "memory");
        } else if (kt + 2 < NK) {
            asm volatile("s_waitcnt vmcnt(4)" ::: "memory");
        } else if (kt + 1 < NK) {
            asm volatile("s_waitcnt vmcnt(0)" ::: "memory");
        }
        __builtin_amdgcn_s_barrier();
    }

    // ---- epilogue: C write ----
#pragma unroll
    for (int m = 0; m < 8; m++)
#pragma unroll
        for (int n = 0; n < 4; n++) {
            const int orow = bi + wm * 128 + m * 16 + fq * 4;
            const int ocol = bj + wn * 64 + n * 16 + fr;
            if (OUTBF) {
                __bf16* o = (__bf16*)C;
#pragma unroll
                for (int e = 0; e < 4; e++)
                    o[(size_t)(orow + e) * NMAT + ocol] = (__bf16)acc[m][n][e];
            } else {
                float* o = (float*)C;
#pragma unroll
                for (int e = 0; e < 4; e++)
                    o[(size_t)(orow + e) * NMAT + ocol] = acc[m][n][e];
            }
        }
}

extern "C" void kernel_launch(void* const* d_in, const int* in_sizes, int n_in,
                              void* d_out, int out_size, void* d_ws, size_t ws_size,
                              hipStream_t stream) {
    (void)in_sizes; (void)n_in; (void)out_size; (void)ws_size;
    const float* matrix = (const float*)d_in[0];
    const float* lower = (const float*)d_in[1];
    float* out = (float*)d_out;
    char* ws = (char*)d_ws;

    __bf16* m0 = (__bf16*)ws;                                // 32 MiB
    __bf16* Lm = (__bf16*)(ws + (size_t)33554432);           // 32 MiB
    __bf16* T1 = (__bf16*)(ws + (size_t)67108864);           // 32 MiB
    float* u   = (float*)(ws + (size_t)100663296);           // 16 KiB
    float* v0  = (float*)(ws + (size_t)100679680);           // 16 KiB
    float* v1  = (float*)(ws + (size_t)100696064);           // 16 KiB

    prep_kernel<<<NMAT, 256, 0, stream>>>(matrix, m0, v1);
    lmask_kernel<<<NMAT, 256, 0, stream>>>(lower, Lm);

    for (int it = 0; it < 20; ++it) {
        float* vp = (it & 1) ? v0 : v1;  // read
        float* vn = (it & 1) ? v1 : v0;  // write (zeroed by rowdots)
        rowdots_kernel<<<1024, 256, 0, stream>>>(m0, vp, u, vn);
        colsums_kernel<<<dim3(4, 64), 256, 0, stream>>>(m0, u, vn);
    }
    // after it=19: u = u_final, v1 = v_final
    invvec_kernel<<<16, 256, 0, stream>>>(u, v1, v0);     // u <- 1/u, v0 <- 1/v1
    rescale_kernel<<<NMAT, 256, 0, stream>>>(m0, u, v0);  // m0 <- diag(r) m0 diag(c)

    gemm_nt<1><<<dim3(16, 16), 512, 0, stream>>>(m0, Lm, (void*)T1);   // T1 = m L^T
    gemm_nt<0><<<dim3(16, 16), 512, 0, stream>>>(T1, m0, (void*)out);  // out = T1 m^T
}